// Round 6
// baseline (244.566 us; speedup 1.0000x reference)
//
#include <hip/hip_runtime.h>

// Problem constants (fixed by setup_inputs): B=8, N=4096, K=3, V=100000,
// H=1024, SEQ=2048. H hard-coded; rest derived from in_sizes.
#define CAP 8            // max sets per (b, pos); dataset has exactly 2
#define MAXT (CAP * 3)   // max tokens per row we track
#define RPB 16           // rows per gather block -> grid = 16384/16 = 1024
#define NPHASE 2         // token-value bands; in-band unique W ~128 MB < L3
#define SPIN_LIMIT 2000  // bounded spin: barrier can only cost, never hang

// Phase 1: scatter each set's token ids into the per-(b,pos) token table.
__global__ void build_map_kernel(const int* __restrict__ pos_ids,
                                 const int* __restrict__ tok,
                                 int total, int n_per, int seq, int K,
                                 int* __restrict__ counts,
                                 int* __restrict__ toktab) {
    int i = blockIdx.x * blockDim.x + threadIdx.x;
    if (i >= total) return;
    int b = i / n_per;
    int p = pos_ids[i];
    if ((unsigned)p >= (unsigned)seq) return;
    int bp = b * seq + p;
    int c = atomicAdd(&counts[bp], 1);
    if (c < CAP) {
        int* dst = toktab + (size_t)bp * (CAP * K) + c * K;
        for (int k = 0; k < K; ++k) dst[k] = tok[i * K + k];
    }
}

#define SORT2(a, b) { int _lo = min(a, b); int _hi = max(a, b); a = _lo; b = _hi; }

// Best-effort grid phase barrier. Correctness does NOT depend on it — it only
// aligns block phases for L3 reuse. Bounded spin, so no deadlock is possible
// even if blocks are not co-resident.
__device__ void soft_barrier(int* ctr, int target) {
    __syncthreads();
    if (threadIdx.x == 0) {
        __hip_atomic_fetch_add(ctr, 1, __ATOMIC_ACQ_REL, __HIP_MEMORY_SCOPE_AGENT);
        int spins = 0;
        while (__hip_atomic_load(ctr, __ATOMIC_ACQUIRE,
                                 __HIP_MEMORY_SCOPE_AGENT) < target) {
            if (++spins > SPIN_LIMIT) break;
            __builtin_amdgcn_s_sleep(16);
        }
    }
    __syncthreads();
}

// Phase 2: persistent-ish gather. 1024 blocks (4/CU x 256 CU co-resident via
// launch_bounds). March over NPHASE ascending token-value bands with a soft
// grid barrier between, so the instantaneous W working set (~V/NPHASE rows)
// is L3-resident and repeated tokens (always same band) hit L3. Per-row sum
// order = ascending token (sorted at load) -> deterministic FP result.
__global__ __launch_bounds__(256, 4)
void gather_phase_kernel(const float* __restrict__ W,
                         const int* __restrict__ counts,
                         const int* __restrict__ toktab,
                         float* __restrict__ out,
                         int* __restrict__ bar,
                         int K, int H, int nrows, int V, int nblocks) {
    int r0 = blockIdx.x * RPB;
    int h = threadIdx.x * 4;  // blockDim.x == H/4
    int stride = CAP * K;

    __shared__ int s_tok[RPB][MAXT];
    __shared__ int s_cnt[RPB];
    __shared__ int s_ntok[RPB];

    if (threadIdx.x < RPB) {
        int r = threadIdx.x;
        int row = r0 + r;
        int cnt = (row < nrows) ? counts[row] : 0;
        int ce = cnt < CAP ? cnt : CAP;
        int n = ce * K; if (n > MAXT) n = MAXT;
        s_cnt[r] = cnt;
        s_ntok[r] = n;
        const int* tp = toktab + (size_t)row * stride;
        if (n == 6) {
            int t0=tp[0],t1=tp[1],t2=tp[2],t3=tp[3],t4=tp[4],t5=tp[5];
            SORT2(t1,t2) SORT2(t4,t5) SORT2(t0,t2) SORT2(t3,t5)
            SORT2(t0,t1) SORT2(t3,t4) SORT2(t1,t4) SORT2(t0,t3)
            SORT2(t2,t5) SORT2(t1,t3) SORT2(t2,t4) SORT2(t2,t3)
            s_tok[r][0]=t0; s_tok[r][1]=t1; s_tok[r][2]=t2;
            s_tok[r][3]=t3; s_tok[r][4]=t4; s_tok[r][5]=t5;
        } else if (n > 0) {
            for (int j = 0; j < n; ++j) s_tok[r][j] = tp[j];
            for (int a = 1; a < n; ++a) {          // LDS insertion sort
                int v = s_tok[r][a]; int q = a - 1;
                while (q >= 0 && s_tok[r][q] > v) {
                    s_tok[r][q + 1] = s_tok[r][q]; --q;
                }
                s_tok[r][q + 1] = v;
            }
        }
    }
    __syncthreads();

    float4 acc[RPB];
    #pragma unroll
    for (int r = 0; r < RPB; ++r) acc[r] = make_float4(0.f, 0.f, 0.f, 0.f);

    for (int ph = 0; ph < NPHASE; ++ph) {
        int lo = (int)(((long long)ph * V) / NPHASE);
        int hi = (int)(((long long)(ph + 1) * V) / NPHASE);
        #pragma unroll
        for (int r = 0; r < RPB; ++r) {
            int n = s_ntok[r];
            for (int j = 0; j < n; ++j) {
                int t = s_tok[r][j];               // wave-uniform
                if (t >= lo && t < hi) {
                    const float4 v = *(const float4*)(W + (size_t)t * H + h);
                    acc[r].x += v.x; acc[r].y += v.y;
                    acc[r].z += v.z; acc[r].w += v.w;
                }
            }
        }
        if (ph + 1 < NPHASE) soft_barrier(&bar[ph], nblocks);
    }

    #pragma unroll
    for (int r = 0; r < RPB; ++r) {
        int row = r0 + r;
        if (row >= nrows) continue;
        int cnt = s_cnt[r];
        float denom = (float)K * (float)(cnt > 0 ? cnt : 1);
        float s = 1.0f / denom;
        float* op = out + (size_t)row * H + h;
        __builtin_nontemporal_store(acc[r].x * s, op + 0);
        __builtin_nontemporal_store(acc[r].y * s, op + 1);
        __builtin_nontemporal_store(acc[r].z * s, op + 2);
        __builtin_nontemporal_store(acc[r].w * s, op + 3);
    }
}

extern "C" void kernel_launch(void* const* d_in, const int* in_sizes, int n_in,
                              void* d_out, int out_size, void* d_ws, size_t ws_size,
                              hipStream_t stream) {
    const int*   pos_ids = (const int*)d_in[0];   // [B*N] int32
    const int*   tok     = (const int*)d_in[1];   // [B*N*K] int32
    // d_in[2]: offsets [B,2]; d_in[3]: seq_len scalar (derived on host)
    const float* W       = (const float*)d_in[4]; // [V*H] f32
    float*       out     = (float*)d_out;         // [B*SEQ*H] f32

    const int B     = in_sizes[2] / 2;
    const int total = in_sizes[0];        // B*N sets
    const int n_per = total / B;          // N
    const int K     = in_sizes[1] / total;
    const int H     = 1024;
    const int seq   = out_size / (B * H);
    const int nrows = B * seq;
    const int V     = in_sizes[4] / H;

    // ws layout: [bar: NPHASE][counts: nrows][toktab: nrows*CAP*K]
    int* bar    = (int*)d_ws;
    int* counts = bar + NPHASE;
    int* toktab = counts + (size_t)nrows;

    // One memset zeroes the barrier state AND counts (graph-replay safe).
    hipMemsetAsync(bar, 0, (size_t)(NPHASE + nrows) * sizeof(int), stream);

    int bthreads = 256;
    int bblocks  = (total + bthreads - 1) / bthreads;
    build_map_kernel<<<bblocks, bthreads, 0, stream>>>(pos_ids, tok, total,
                                                       n_per, seq, K,
                                                       counts, toktab);

    int gblocks = (nrows + RPB - 1) / RPB;   // 1024 = 4/CU x 256 CU
    gather_phase_kernel<<<gblocks, H / 4, 0, stream>>>(W, counts, toktab,
                                                       out, bar, K, H,
                                                       nrows, V, gblocks);
}